// Round 2
// baseline (149.869 us; speedup 1.0000x reference)
//
#include <hip/hip_runtime.h>

#define NBLOCKS 4096
#define NTHREADS 256
#define UNROLL 4
#define NUM_LEVELS 101

// Stage 1: weighted-SSE partial sums, one float per block (plain store).
// Structure: issue wt-table load, then ALL 8 bulk loads (32 data VGPRs, still
// under the 64-VGPR / 8-waves-per-SIMD cliff), then LDS-stage the table and
// barrier (vmcnt wait drains only the table load), then compute with
// progressive vmcnt waits. sched_barrier(0) pins the load phase so the
// compiler cannot re-sink loads into the compute rounds (round-0/1 showed it
// does exactly that: VGPR_Count=36 proves just-in-time rounds, each exposing
// full loaded latency).
__global__ __launch_bounds__(NTHREADS) void wmse_partial(
    const float* __restrict__ x,
    const float* __restrict__ y,
    const float* __restrict__ wt,
    float* __restrict__ partial, int n)
{
    __shared__ float s_wt[NUM_LEVELS];
    __shared__ float s_red[NTHREADS / 64];

    const float4* __restrict__ x4 = (const float4*)x;
    const float4* __restrict__ y4 = (const float4*)y;
    const int n4 = n >> 2;                 // N = 2^24 -> 4,194,304 float4s
    const int stride = NBLOCKS * NTHREADS; // 1,048,576
    const int base = blockIdx.x * NTHREADS + threadIdx.x;

    float acc = 0.f;

    if (n4 == UNROLL * stride) {
        // ---- load phase: table load FIRST, then 8 bulk loads ----
        float wval = 0.f;
        if (threadIdx.x < NUM_LEVELS) wval = wt[threadIdx.x];

        float4 xs[UNROLL], ys[UNROLL];
        #pragma unroll
        for (int k = 0; k < UNROLL; ++k) {
            ys[k] = y4[base + k * stride];
            xs[k] = x4[base + k * stride];
        }
        __builtin_amdgcn_sched_barrier(0);  // pin: all loads issued before anything below

        // ---- stage table to LDS; barrier waits only vmcnt(8) for wval ----
        if (threadIdx.x < NUM_LEVELS) s_wt[threadIdx.x] = wval;
        __syncthreads();

        // ---- compute phase: progressive vmcnt waits, ds_read pipeline ----
        float a0 = 0.f, a1 = 0.f;
        #pragma unroll
        for (int k = 0; k < UNROLL; ++k) {
            float4 xv = xs[k], yv = ys[k];
            float w0 = s_wt[__float2int_rn(yv.x * 100.f)];
            float w1 = s_wt[__float2int_rn(yv.y * 100.f)];
            float w2 = s_wt[__float2int_rn(yv.z * 100.f)];
            float w3 = s_wt[__float2int_rn(yv.w * 100.f)];
            float d0 = xv.x - yv.x, d1 = xv.y - yv.y;
            float d2 = xv.z - yv.z, d3 = xv.w - yv.w;
            a0 += d0 * d0 * w0 + d2 * d2 * w2;
            a1 += d1 * d1 * w1 + d3 * d3 * w3;
        }
        acc = a0 + a1;
    } else {
        // Generic fallback path.
        for (int i = threadIdx.x; i < NUM_LEVELS; i += NTHREADS) s_wt[i] = wt[i];
        __syncthreads();
        for (int i = base; i < n4; i += stride) {
            float4 xv = x4[i], yv = y4[i];
            float w0 = s_wt[__float2int_rn(yv.x * 100.f)];
            float w1 = s_wt[__float2int_rn(yv.y * 100.f)];
            float w2 = s_wt[__float2int_rn(yv.z * 100.f)];
            float w3 = s_wt[__float2int_rn(yv.w * 100.f)];
            float d0 = xv.x - yv.x, d1 = xv.y - yv.y;
            float d2 = xv.z - yv.z, d3 = xv.w - yv.w;
            acc += d0 * d0 * w0 + d1 * d1 * w1 + d2 * d2 * w2 + d3 * d3 * w3;
        }
    }

    // wave-64 shuffle reduction
    #pragma unroll
    for (int off = 32; off > 0; off >>= 1)
        acc += __shfl_down(acc, off, 64);

    const int lane = threadIdx.x & 63;
    const int wave = threadIdx.x >> 6;
    if (lane == 0) s_red[wave] = acc;
    __syncthreads();
    if (threadIdx.x == 0) {
        float s = 0.f;
        #pragma unroll
        for (int w = 0; w < NTHREADS / 64; ++w) s += s_red[w];
        partial[blockIdx.x] = s;   // plain store, no atomic
    }
}

// Stage 2: one block folds the partials and writes the final mean.
// Overwrites the poisoned output directly -> no memset node needed.
__global__ __launch_bounds__(NTHREADS) void wmse_reduce(
    const float* __restrict__ partial, float* __restrict__ out, float inv_n)
{
    __shared__ float s_red[NTHREADS / 64];
    float acc = 0.f;
    #pragma unroll
    for (int k = 0; k < NBLOCKS / NTHREADS; ++k)
        acc += partial[threadIdx.x + k * NTHREADS];

    #pragma unroll
    for (int off = 32; off > 0; off >>= 1)
        acc += __shfl_down(acc, off, 64);

    const int lane = threadIdx.x & 63;
    const int wave = threadIdx.x >> 6;
    if (lane == 0) s_red[wave] = acc;
    __syncthreads();
    if (threadIdx.x == 0) {
        float s = 0.f;
        #pragma unroll
        for (int w = 0; w < NTHREADS / 64; ++w) s += s_red[w];
        *out = s * inv_n;
    }
}

// Fallback (workspace too small): atomic single-kernel version.
__global__ __launch_bounds__(NTHREADS) void wmse_fused_atomic(
    const float* __restrict__ x,
    const float* __restrict__ y,
    const float* __restrict__ wt,
    float* __restrict__ out, int n, float inv_n)
{
    __shared__ float s_wt[NUM_LEVELS];
    __shared__ float s_red[NTHREADS / 64];

    for (int i = threadIdx.x; i < NUM_LEVELS; i += NTHREADS) s_wt[i] = wt[i];
    __syncthreads();

    const float4* __restrict__ x4 = (const float4*)x;
    const float4* __restrict__ y4 = (const float4*)y;
    const int n4 = n >> 2;
    const int stride = NBLOCKS * NTHREADS;
    const int base = blockIdx.x * NTHREADS + threadIdx.x;

    float acc = 0.f;
    for (int i = base; i < n4; i += stride) {
        float4 xv = x4[i], yv = y4[i];
        float w0 = s_wt[__float2int_rn(yv.x * 100.f)];
        float w1 = s_wt[__float2int_rn(yv.y * 100.f)];
        float w2 = s_wt[__float2int_rn(yv.z * 100.f)];
        float w3 = s_wt[__float2int_rn(yv.w * 100.f)];
        float d0 = xv.x - yv.x, d1 = xv.y - yv.y;
        float d2 = xv.z - yv.z, d3 = xv.w - yv.w;
        acc += d0 * d0 * w0 + d1 * d1 * w1 + d2 * d2 * w2 + d3 * d3 * w3;
    }

    #pragma unroll
    for (int off = 32; off > 0; off >>= 1)
        acc += __shfl_down(acc, off, 64);

    const int lane = threadIdx.x & 63;
    const int wave = threadIdx.x >> 6;
    if (lane == 0) s_red[wave] = acc;
    __syncthreads();
    if (threadIdx.x == 0) {
        float s = 0.f;
        #pragma unroll
        for (int w = 0; w < NTHREADS / 64; ++w) s += s_red[w];
        atomicAdd(out, s * inv_n);
    }
}

extern "C" void kernel_launch(void* const* d_in, const int* in_sizes, int n_in,
                              void* d_out, int out_size, void* d_ws, size_t ws_size,
                              hipStream_t stream) {
    const float* x  = (const float*)d_in[0];
    const float* y  = (const float*)d_in[1];
    const float* wt = (const float*)d_in[2];
    float* out = (float*)d_out;
    const int n = in_sizes[0];
    const float inv_n = 1.0f / (float)n;

    if (d_ws && ws_size >= NBLOCKS * sizeof(float)) {
        float* partial = (float*)d_ws;
        wmse_partial<<<NBLOCKS, NTHREADS, 0, stream>>>(x, y, wt, partial, n);
        wmse_reduce<<<1, NTHREADS, 0, stream>>>(partial, out, inv_n);
    } else {
        hipMemsetAsync(out, 0, sizeof(float), stream);
        wmse_fused_atomic<<<NBLOCKS, NTHREADS, 0, stream>>>(x, y, wt, out, n, inv_n);
    }
}

// Round 3
// 147.657 us; speedup vs baseline: 1.0150x; 1.0150x over previous
//
#include <hip/hip_runtime.h>

#define NBLOCKS 4096
#define NTHREADS 256
#define UNROLL 4
#define NUM_LEVELS 101

// Force-materialize a loaded float4 pair at this program point.
// volatile + memory clobber: loads cannot be sunk below this, the compiler
// must emit a (minimal, progressive) s_waitcnt vmcnt(N) here, and the values
// must live in VGPRs -> the 8-deep load pipeline actually materializes.
// Rounds 0-2 proved the compiler otherwise rewrites it to just-in-time
// load/use (VGPR_Count 36/24), exposing full memory latency per iteration.
#define BALLAST4x2(a, b)                                              \
    asm volatile("" ::"v"((a).x), "v"((a).y), "v"((a).z), "v"((a).w), \
                     "v"((b).x), "v"((b).y), "v"((b).z), "v"((b).w)   \
                 : "memory")

// Stage 1: weighted-SSE partial sums, one float per block (plain store).
__global__ __launch_bounds__(NTHREADS) void wmse_partial(
    const float* __restrict__ x,
    const float* __restrict__ y,
    const float* __restrict__ wt,
    float* __restrict__ partial, int n)
{
    __shared__ float s_wt[NUM_LEVELS];
    __shared__ float s_red[NTHREADS / 64];

    const float4* __restrict__ x4 = (const float4*)x;
    const float4* __restrict__ y4 = (const float4*)y;
    const int n4 = n >> 2;                 // N = 2^24 -> 4,194,304 float4s
    const int stride = NBLOCKS * NTHREADS; // 1,048,576
    const int base = blockIdx.x * NTHREADS + threadIdx.x;

    float acc = 0.f;

    if (n4 == UNROLL * stride) {
        // ---- table to LDS first; this barrier's full vmcnt drain only
        //      covers the 404-byte table load, not the bulk pipeline ----
        if (threadIdx.x < NUM_LEVELS) s_wt[threadIdx.x] = wt[threadIdx.x];
        __syncthreads();

        // ---- issue ALL 8 bulk loads (4 KB/wave in flight) ----
        float4 xs[UNROLL], ys[UNROLL];
        #pragma unroll
        for (int k = 0; k < UNROLL; ++k) {
            ys[k] = y4[base + k * stride];
            xs[k] = x4[base + k * stride];
        }

        // ---- compute with progressive vmcnt waits (ballast pins each k) ----
        float a0 = 0.f, a1 = 0.f;
        #pragma unroll
        for (int k = 0; k < UNROLL; ++k) {
            BALLAST4x2(ys[k], xs[k]);
            float4 xv = xs[k], yv = ys[k];
            float w0 = s_wt[__float2int_rn(yv.x * 100.f)];
            float w1 = s_wt[__float2int_rn(yv.y * 100.f)];
            float w2 = s_wt[__float2int_rn(yv.z * 100.f)];
            float w3 = s_wt[__float2int_rn(yv.w * 100.f)];
            float d0 = xv.x - yv.x, d1 = xv.y - yv.y;
            float d2 = xv.z - yv.z, d3 = xv.w - yv.w;
            a0 += d0 * d0 * w0 + d2 * d2 * w2;
            a1 += d1 * d1 * w1 + d3 * d3 * w3;
        }
        acc = a0 + a1;
    } else {
        // Generic fallback path.
        for (int i = threadIdx.x; i < NUM_LEVELS; i += NTHREADS) s_wt[i] = wt[i];
        __syncthreads();
        for (int i = base; i < n4; i += stride) {
            float4 xv = x4[i], yv = y4[i];
            float w0 = s_wt[__float2int_rn(yv.x * 100.f)];
            float w1 = s_wt[__float2int_rn(yv.y * 100.f)];
            float w2 = s_wt[__float2int_rn(yv.z * 100.f)];
            float w3 = s_wt[__float2int_rn(yv.w * 100.f)];
            float d0 = xv.x - yv.x, d1 = xv.y - yv.y;
            float d2 = xv.z - yv.z, d3 = xv.w - yv.w;
            acc += d0 * d0 * w0 + d1 * d1 * w1 + d2 * d2 * w2 + d3 * d3 * w3;
        }
    }

    // wave-64 shuffle reduction
    #pragma unroll
    for (int off = 32; off > 0; off >>= 1)
        acc += __shfl_down(acc, off, 64);

    const int lane = threadIdx.x & 63;
    const int wave = threadIdx.x >> 6;
    if (lane == 0) s_red[wave] = acc;
    __syncthreads();
    if (threadIdx.x == 0) {
        float s = 0.f;
        #pragma unroll
        for (int w = 0; w < NTHREADS / 64; ++w) s += s_red[w];
        partial[blockIdx.x] = s;   // plain store, no atomic
    }
}

// Stage 2: one block folds the partials and writes the final mean.
// Overwrites the poisoned output directly -> no memset node needed.
__global__ __launch_bounds__(NTHREADS) void wmse_reduce(
    const float* __restrict__ partial, float* __restrict__ out, float inv_n)
{
    __shared__ float s_red[NTHREADS / 64];
    float acc = 0.f;
    #pragma unroll
    for (int k = 0; k < NBLOCKS / NTHREADS; ++k)
        acc += partial[threadIdx.x + k * NTHREADS];

    #pragma unroll
    for (int off = 32; off > 0; off >>= 1)
        acc += __shfl_down(acc, off, 64);

    const int lane = threadIdx.x & 63;
    const int wave = threadIdx.x >> 6;
    if (lane == 0) s_red[wave] = acc;
    __syncthreads();
    if (threadIdx.x == 0) {
        float s = 0.f;
        #pragma unroll
        for (int w = 0; w < NTHREADS / 64; ++w) s += s_red[w];
        *out = s * inv_n;
    }
}

// Fallback (workspace too small): atomic single-kernel version.
__global__ __launch_bounds__(NTHREADS) void wmse_fused_atomic(
    const float* __restrict__ x,
    const float* __restrict__ y,
    const float* __restrict__ wt,
    float* __restrict__ out, int n, float inv_n)
{
    __shared__ float s_wt[NUM_LEVELS];
    __shared__ float s_red[NTHREADS / 64];

    for (int i = threadIdx.x; i < NUM_LEVELS; i += NTHREADS) s_wt[i] = wt[i];
    __syncthreads();

    const float4* __restrict__ x4 = (const float4*)x;
    const float4* __restrict__ y4 = (const float4*)y;
    const int n4 = n >> 2;
    const int stride = NBLOCKS * NTHREADS;
    const int base = blockIdx.x * NTHREADS + threadIdx.x;

    float acc = 0.f;
    for (int i = base; i < n4; i += stride) {
        float4 xv = x4[i], yv = y4[i];
        float w0 = s_wt[__float2int_rn(yv.x * 100.f)];
        float w1 = s_wt[__float2int_rn(yv.y * 100.f)];
        float w2 = s_wt[__float2int_rn(yv.z * 100.f)];
        float w3 = s_wt[__float2int_rn(yv.w * 100.f)];
        float d0 = xv.x - yv.x, d1 = xv.y - yv.y;
        float d2 = xv.z - yv.z, d3 = xv.w - yv.w;
        acc += d0 * d0 * w0 + d1 * d1 * w1 + d2 * d2 * w2 + d3 * d3 * w3;
    }

    #pragma unroll
    for (int off = 32; off > 0; off >>= 1)
        acc += __shfl_down(acc, off, 64);

    const int lane = threadIdx.x & 63;
    const int wave = threadIdx.x >> 6;
    if (lane == 0) s_red[wave] = acc;
    __syncthreads();
    if (threadIdx.x == 0) {
        float s = 0.f;
        #pragma unroll
        for (int w = 0; w < NTHREADS / 64; ++w) s += s_red[w];
        atomicAdd(out, s * inv_n);
    }
}

extern "C" void kernel_launch(void* const* d_in, const int* in_sizes, int n_in,
                              void* d_out, int out_size, void* d_ws, size_t ws_size,
                              hipStream_t stream) {
    const float* x  = (const float*)d_in[0];
    const float* y  = (const float*)d_in[1];
    const float* wt = (const float*)d_in[2];
    float* out = (float*)d_out;
    const int n = in_sizes[0];
    const float inv_n = 1.0f / (float)n;

    if (d_ws && ws_size >= NBLOCKS * sizeof(float)) {
        float* partial = (float*)d_ws;
        wmse_partial<<<NBLOCKS, NTHREADS, 0, stream>>>(x, y, wt, partial, n);
        wmse_reduce<<<1, NTHREADS, 0, stream>>>(partial, out, inv_n);
    } else {
        hipMemsetAsync(out, 0, sizeof(float), stream);
        wmse_fused_atomic<<<NBLOCKS, NTHREADS, 0, stream>>>(x, y, wt, out, n, inv_n);
    }
}

// Round 4
// 146.297 us; speedup vs baseline: 1.0244x; 1.0093x over previous
//
#include <hip/hip_runtime.h>

#define NBLOCKS 2048
#define NTHREADS 256
#define ITERS 8              // n4 == NBLOCKS*NTHREADS*ITERS for N=2^24
#define NUM_LEVELS 101

// Volatile pass-through pin: forces the s_waitcnt for this value HERE (its
// first use), while independent later loads are free to hoist above it.
// Gives a counted-vmcnt rolling pipeline from plain source with only 1-deep
// (16 VGPR) pressure -- rounds 1-3 showed 8-deep gets collapsed by the
// scheduler (VGPR_Count stayed 24).
#define PIN4(v) asm volatile("" : "+v"((v).x), "+v"((v).y), "+v"((v).z), "+v"((v).w))

// Stage 1: weighted-SSE partial sums, one float per block (plain store).
// Per-block CONTIGUOUS 32-KB windows per array (sequential streaming like the
// 4.9-5.2 TB/s norm kernels), rolling double-buffer prefetch.
__global__ __launch_bounds__(NTHREADS) void wmse_partial(
    const float* __restrict__ x,
    const float* __restrict__ y,
    const float* __restrict__ wt,
    float* __restrict__ partial, int n)
{
    __shared__ float s_wt[NUM_LEVELS];
    __shared__ float s_red[NTHREADS / 64];

    const float4* __restrict__ x4 = (const float4*)x;
    const float4* __restrict__ y4 = (const float4*)y;
    const int n4 = n >> 2;

    float acc = 0.f;

    if (n4 == NBLOCKS * NTHREADS * ITERS) {
        // table -> LDS once; barrier drains only the 404-B table load
        if (threadIdx.x < NUM_LEVELS) s_wt[threadIdx.x] = wt[threadIdx.x];
        __syncthreads();

        // contiguous per-block segment: block walks 32 KB sequentially
        const int seg = blockIdx.x * (NTHREADS * ITERS);
        const int i0 = seg + threadIdx.x;

        float4 yc = y4[i0];
        float4 xc = x4[i0];

        float a0 = 0.f, a1 = 0.f;
        #pragma unroll
        for (int k = 0; k < ITERS - 1; ++k) {
            const int in = i0 + (k + 1) * NTHREADS;
            float4 yn = y4[in];          // issue next (hoists above the pin)
            float4 xn = x4[in];
            PIN4(yc); PIN4(xc);          // vmcnt wait for CURRENT lands here
            float w0 = s_wt[__float2int_rn(yc.x * 100.f)];
            float w1 = s_wt[__float2int_rn(yc.y * 100.f)];
            float w2 = s_wt[__float2int_rn(yc.z * 100.f)];
            float w3 = s_wt[__float2int_rn(yc.w * 100.f)];
            float d0 = xc.x - yc.x, d1 = xc.y - yc.y;
            float d2 = xc.z - yc.z, d3 = xc.w - yc.w;
            a0 += d0 * d0 * w0 + d2 * d2 * w2;
            a1 += d1 * d1 * w1 + d3 * d3 * w3;
            yc = yn; xc = xn;
        }
        // last iteration
        PIN4(yc); PIN4(xc);
        {
            float w0 = s_wt[__float2int_rn(yc.x * 100.f)];
            float w1 = s_wt[__float2int_rn(yc.y * 100.f)];
            float w2 = s_wt[__float2int_rn(yc.z * 100.f)];
            float w3 = s_wt[__float2int_rn(yc.w * 100.f)];
            float d0 = xc.x - yc.x, d1 = xc.y - yc.y;
            float d2 = xc.z - yc.z, d3 = xc.w - yc.w;
            a0 += d0 * d0 * w0 + d2 * d2 * w2;
            a1 += d1 * d1 * w1 + d3 * d3 * w3;
        }
        acc = a0 + a1;
    } else {
        // Generic fallback path (grid-stride).
        for (int i = threadIdx.x; i < NUM_LEVELS; i += NTHREADS) s_wt[i] = wt[i];
        __syncthreads();
        const int stride = NBLOCKS * NTHREADS;
        for (int i = blockIdx.x * NTHREADS + threadIdx.x; i < n4; i += stride) {
            float4 xv = x4[i], yv = y4[i];
            float w0 = s_wt[__float2int_rn(yv.x * 100.f)];
            float w1 = s_wt[__float2int_rn(yv.y * 100.f)];
            float w2 = s_wt[__float2int_rn(yv.z * 100.f)];
            float w3 = s_wt[__float2int_rn(yv.w * 100.f)];
            float d0 = xv.x - yv.x, d1 = xv.y - yv.y;
            float d2 = xv.z - yv.z, d3 = xv.w - yv.w;
            acc += d0 * d0 * w0 + d1 * d1 * w1 + d2 * d2 * w2 + d3 * d3 * w3;
        }
    }

    // wave-64 shuffle reduction
    #pragma unroll
    for (int off = 32; off > 0; off >>= 1)
        acc += __shfl_down(acc, off, 64);

    const int lane = threadIdx.x & 63;
    const int wave = threadIdx.x >> 6;
    if (lane == 0) s_red[wave] = acc;
    __syncthreads();
    if (threadIdx.x == 0) {
        float s = 0.f;
        #pragma unroll
        for (int w = 0; w < NTHREADS / 64; ++w) s += s_red[w];
        partial[blockIdx.x] = s;   // plain store, no atomic
    }
}

// Stage 2: one block folds the partials and writes the final mean.
// Overwrites the poisoned output directly -> no memset node needed.
__global__ __launch_bounds__(NTHREADS) void wmse_reduce(
    const float* __restrict__ partial, float* __restrict__ out, float inv_n)
{
    __shared__ float s_red[NTHREADS / 64];
    float acc = 0.f;
    #pragma unroll
    for (int k = 0; k < NBLOCKS / NTHREADS; ++k)
        acc += partial[threadIdx.x + k * NTHREADS];

    #pragma unroll
    for (int off = 32; off > 0; off >>= 1)
        acc += __shfl_down(acc, off, 64);

    const int lane = threadIdx.x & 63;
    const int wave = threadIdx.x >> 6;
    if (lane == 0) s_red[wave] = acc;
    __syncthreads();
    if (threadIdx.x == 0) {
        float s = 0.f;
        #pragma unroll
        for (int w = 0; w < NTHREADS / 64; ++w) s += s_red[w];
        *out = s * inv_n;
    }
}

// Fallback (workspace too small): atomic single-kernel version.
__global__ __launch_bounds__(NTHREADS) void wmse_fused_atomic(
    const float* __restrict__ x,
    const float* __restrict__ y,
    const float* __restrict__ wt,
    float* __restrict__ out, int n, float inv_n)
{
    __shared__ float s_wt[NUM_LEVELS];
    __shared__ float s_red[NTHREADS / 64];

    for (int i = threadIdx.x; i < NUM_LEVELS; i += NTHREADS) s_wt[i] = wt[i];
    __syncthreads();

    const float4* __restrict__ x4 = (const float4*)x;
    const float4* __restrict__ y4 = (const float4*)y;
    const int n4 = n >> 2;
    const int stride = NBLOCKS * NTHREADS;
    const int base = blockIdx.x * NTHREADS + threadIdx.x;

    float acc = 0.f;
    for (int i = base; i < n4; i += stride) {
        float4 xv = x4[i], yv = y4[i];
        float w0 = s_wt[__float2int_rn(yv.x * 100.f)];
        float w1 = s_wt[__float2int_rn(yv.y * 100.f)];
        float w2 = s_wt[__float2int_rn(yv.z * 100.f)];
        float w3 = s_wt[__float2int_rn(yv.w * 100.f)];
        float d0 = xv.x - yv.x, d1 = xv.y - yv.y;
        float d2 = xv.z - yv.z, d3 = xv.w - yv.w;
        acc += d0 * d0 * w0 + d1 * d1 * w1 + d2 * d2 * w2 + d3 * d3 * w3;
    }

    #pragma unroll
    for (int off = 32; off > 0; off >>= 1)
        acc += __shfl_down(acc, off, 64);

    const int lane = threadIdx.x & 63;
    const int wave = threadIdx.x >> 6;
    if (lane == 0) s_red[wave] = acc;
    __syncthreads();
    if (threadIdx.x == 0) {
        float s = 0.f;
        #pragma unroll
        for (int w = 0; w < NTHREADS / 64; ++w) s += s_red[w];
        atomicAdd(out, s * inv_n);
    }
}

extern "C" void kernel_launch(void* const* d_in, const int* in_sizes, int n_in,
                              void* d_out, int out_size, void* d_ws, size_t ws_size,
                              hipStream_t stream) {
    const float* x  = (const float*)d_in[0];
    const float* y  = (const float*)d_in[1];
    const float* wt = (const float*)d_in[2];
    float* out = (float*)d_out;
    const int n = in_sizes[0];
    const float inv_n = 1.0f / (float)n;

    if (d_ws && ws_size >= NBLOCKS * sizeof(float)) {
        float* partial = (float*)d_ws;
        wmse_partial<<<NBLOCKS, NTHREADS, 0, stream>>>(x, y, wt, partial, n);
        wmse_reduce<<<1, NTHREADS, 0, stream>>>(partial, out, inv_n);
    } else {
        hipMemsetAsync(out, 0, sizeof(float), stream);
        wmse_fused_atomic<<<NBLOCKS, NTHREADS, 0, stream>>>(x, y, wt, out, n, inv_n);
    }
}

// Round 5
// 140.186 us; speedup vs baseline: 1.0691x; 1.0436x over previous
//
#include <hip/hip_runtime.h>

#define NBLOCKS 2048
#define NTHREADS 256
#define ITERS 8              // n4 == NBLOCKS*NTHREADS*ITERS for N=2^24
#define NUM_LEVELS 101

typedef float f32x4 __attribute__((ext_vector_type(4)));

// Stage 1: weighted-SSE partial sums, one float per block (plain store).
// Bulk loads are NONTEMPORAL: rounds 0-4 showed duration is invariant (~44us)
// to schedule/occupancy/access-shape, with FETCH_SIZE pinned at exactly one
// array (64 MB) from HBM and the other array served from L3. Arithmetic:
// 67 MB L3-hit at ~1.5 TB/s effective = 44.7 us == measured duration -> the
// L3-hit stream is the pacer. nt loads stop L2/L3 retention of stream-once
// data so both arrays stream from HBM (~6.3 TB/s achievable).
__global__ __launch_bounds__(NTHREADS) void wmse_partial(
    const float* __restrict__ x,
    const float* __restrict__ y,
    const float* __restrict__ wt,
    float* __restrict__ partial, int n)
{
    __shared__ float s_wt[NUM_LEVELS];
    __shared__ float s_red[NTHREADS / 64];

    const f32x4* __restrict__ x4 = (const f32x4*)x;
    const f32x4* __restrict__ y4 = (const f32x4*)y;
    const int n4 = n >> 2;

    float acc = 0.f;

    if (n4 == NBLOCKS * NTHREADS * ITERS) {
        // weight table -> LDS with NORMAL (cached) loads; tiny and reused.
        if (threadIdx.x < NUM_LEVELS) s_wt[threadIdx.x] = wt[threadIdx.x];
        __syncthreads();

        // contiguous per-block segment (same shape as round 4)
        const int i0 = blockIdx.x * (NTHREADS * ITERS) + threadIdx.x;

        float a0 = 0.f, a1 = 0.f;
        #pragma unroll
        for (int k = 0; k < ITERS; ++k) {
            const int i = i0 + k * NTHREADS;
            f32x4 yv = __builtin_nontemporal_load(y4 + i);
            f32x4 xv = __builtin_nontemporal_load(x4 + i);
            float w0 = s_wt[__float2int_rn(yv[0] * 100.f)];
            float w1 = s_wt[__float2int_rn(yv[1] * 100.f)];
            float w2 = s_wt[__float2int_rn(yv[2] * 100.f)];
            float w3 = s_wt[__float2int_rn(yv[3] * 100.f)];
            float d0 = xv[0] - yv[0], d1 = xv[1] - yv[1];
            float d2 = xv[2] - yv[2], d3 = xv[3] - yv[3];
            a0 += d0 * d0 * w0 + d2 * d2 * w2;
            a1 += d1 * d1 * w1 + d3 * d3 * w3;
        }
        acc = a0 + a1;
    } else {
        // Generic fallback path (grid-stride, normal loads).
        for (int i = threadIdx.x; i < NUM_LEVELS; i += NTHREADS) s_wt[i] = wt[i];
        __syncthreads();
        const int stride = NBLOCKS * NTHREADS;
        for (int i = blockIdx.x * NTHREADS + threadIdx.x; i < n4; i += stride) {
            f32x4 xv = x4[i], yv = y4[i];
            float w0 = s_wt[__float2int_rn(yv[0] * 100.f)];
            float w1 = s_wt[__float2int_rn(yv[1] * 100.f)];
            float w2 = s_wt[__float2int_rn(yv[2] * 100.f)];
            float w3 = s_wt[__float2int_rn(yv[3] * 100.f)];
            float d0 = xv[0] - yv[0], d1 = xv[1] - yv[1];
            float d2 = xv[2] - yv[2], d3 = xv[3] - yv[3];
            acc += d0 * d0 * w0 + d1 * d1 * w1 + d2 * d2 * w2 + d3 * d3 * w3;
        }
    }

    // wave-64 shuffle reduction
    #pragma unroll
    for (int off = 32; off > 0; off >>= 1)
        acc += __shfl_down(acc, off, 64);

    const int lane = threadIdx.x & 63;
    const int wave = threadIdx.x >> 6;
    if (lane == 0) s_red[wave] = acc;
    __syncthreads();
    if (threadIdx.x == 0) {
        float s = 0.f;
        #pragma unroll
        for (int w = 0; w < NTHREADS / 64; ++w) s += s_red[w];
        partial[blockIdx.x] = s;   // plain store, no atomic
    }
}

// Stage 2: one block folds the partials and writes the final mean.
// Overwrites the poisoned output directly -> no memset node needed.
__global__ __launch_bounds__(NTHREADS) void wmse_reduce(
    const float* __restrict__ partial, float* __restrict__ out, float inv_n)
{
    __shared__ float s_red[NTHREADS / 64];
    float acc = 0.f;
    #pragma unroll
    for (int k = 0; k < NBLOCKS / NTHREADS; ++k)
        acc += partial[threadIdx.x + k * NTHREADS];

    #pragma unroll
    for (int off = 32; off > 0; off >>= 1)
        acc += __shfl_down(acc, off, 64);

    const int lane = threadIdx.x & 63;
    const int wave = threadIdx.x >> 6;
    if (lane == 0) s_red[wave] = acc;
    __syncthreads();
    if (threadIdx.x == 0) {
        float s = 0.f;
        #pragma unroll
        for (int w = 0; w < NTHREADS / 64; ++w) s += s_red[w];
        *out = s * inv_n;
    }
}

// Fallback (workspace too small): atomic single-kernel version.
__global__ __launch_bounds__(NTHREADS) void wmse_fused_atomic(
    const float* __restrict__ x,
    const float* __restrict__ y,
    const float* __restrict__ wt,
    float* __restrict__ out, int n, float inv_n)
{
    __shared__ float s_wt[NUM_LEVELS];
    __shared__ float s_red[NTHREADS / 64];

    for (int i = threadIdx.x; i < NUM_LEVELS; i += NTHREADS) s_wt[i] = wt[i];
    __syncthreads();

    const f32x4* __restrict__ x4 = (const f32x4*)x;
    const f32x4* __restrict__ y4 = (const f32x4*)y;
    const int n4 = n >> 2;
    const int stride = NBLOCKS * NTHREADS;
    const int base = blockIdx.x * NTHREADS + threadIdx.x;

    float acc = 0.f;
    for (int i = base; i < n4; i += stride) {
        f32x4 xv = x4[i], yv = y4[i];
        float w0 = s_wt[__float2int_rn(yv[0] * 100.f)];
        float w1 = s_wt[__float2int_rn(yv[1] * 100.f)];
        float w2 = s_wt[__float2int_rn(yv[2] * 100.f)];
        float w3 = s_wt[__float2int_rn(yv[3] * 100.f)];
        float d0 = xv[0] - yv[0], d1 = xv[1] - yv[1];
        float d2 = xv[2] - yv[2], d3 = xv[3] - yv[3];
        acc += d0 * d0 * w0 + d1 * d1 * w1 + d2 * d2 * w2 + d3 * d3 * w3;
    }

    #pragma unroll
    for (int off = 32; off > 0; off >>= 1)
        acc += __shfl_down(acc, off, 64);

    const int lane = threadIdx.x & 63;
    const int wave = threadIdx.x >> 6;
    if (lane == 0) s_red[wave] = acc;
    __syncthreads();
    if (threadIdx.x == 0) {
        float s = 0.f;
        #pragma unroll
        for (int w = 0; w < NTHREADS / 64; ++w) s += s_red[w];
        atomicAdd(out, s * inv_n);
    }
}

extern "C" void kernel_launch(void* const* d_in, const int* in_sizes, int n_in,
                              void* d_out, int out_size, void* d_ws, size_t ws_size,
                              hipStream_t stream) {
    const float* x  = (const float*)d_in[0];
    const float* y  = (const float*)d_in[1];
    const float* wt = (const float*)d_in[2];
    float* out = (float*)d_out;
    const int n = in_sizes[0];
    const float inv_n = 1.0f / (float)n;

    if (d_ws && ws_size >= NBLOCKS * sizeof(float)) {
        float* partial = (float*)d_ws;
        wmse_partial<<<NBLOCKS, NTHREADS, 0, stream>>>(x, y, wt, partial, n);
        wmse_reduce<<<1, NTHREADS, 0, stream>>>(partial, out, inv_n);
    } else {
        hipMemsetAsync(out, 0, sizeof(float), stream);
        wmse_fused_atomic<<<NBLOCKS, NTHREADS, 0, stream>>>(x, y, wt, out, n, inv_n);
    }
}

// Round 6
// 137.813 us; speedup vs baseline: 1.0875x; 1.0172x over previous
//
#include <hip/hip_runtime.h>

#define NBLOCKS 2048
#define NTHREADS 256
#define VPT 8                // float4s per array per thread; n4 == NBLOCKS*NTHREADS*VPT
#define OUTER 4              // steps of 2 float4s each
#define NUM_LEVELS 101

typedef float f32x4 __attribute__((ext_vector_type(4)));

// Pass-through pin (NO memory clobber): forces the s_waitcnt for these values
// here, while independent later nt-loads are free to hoist above -> rolling
// counted-vmcnt pipeline. Round 4 showed this form does materialize (+VGPRs),
// unlike the 8-deep variants the scheduler collapsed.
#define PIN4(v) asm volatile("" : "+v"((v)[0]), "+v"((v)[1]), "+v"((v)[2]), "+v"((v)[3]))

#define GATHER_ACC(yv, xv)                                   \
    do {                                                     \
        float w0 = s_wt[__float2int_rn((yv)[0] * 100.f)];    \
        float w1 = s_wt[__float2int_rn((yv)[1] * 100.f)];    \
        float w2 = s_wt[__float2int_rn((yv)[2] * 100.f)];    \
        float w3 = s_wt[__float2int_rn((yv)[3] * 100.f)];    \
        float d0 = (xv)[0] - (yv)[0], d1 = (xv)[1] - (yv)[1];\
        float d2 = (xv)[2] - (yv)[2], d3 = (xv)[3] - (yv)[3];\
        a0 += d0 * d0 * w0 + d2 * d2 * w2;                   \
        a1 += d1 * d1 * w1 + d3 * d3 * w3;                   \
    } while (0)

// Stage 1: weighted-SSE partial sums, one float per block (plain store).
// nt loads (round 5: kernel dropped below the 40us fill kernels -> HBM-stream
// regime). Now the pipeline matters: 2x float4 per array per step + 1-deep
// rolling prefetch = 4x outstanding bytes/wave vs the JIT schedule.
__global__ __launch_bounds__(NTHREADS) void wmse_partial(
    const float* __restrict__ x,
    const float* __restrict__ y,
    const float* __restrict__ wt,
    float* __restrict__ partial, int n)
{
    __shared__ float s_wt[NUM_LEVELS];
    __shared__ float s_red[NTHREADS / 64];

    const f32x4* __restrict__ x4 = (const f32x4*)x;
    const f32x4* __restrict__ y4 = (const f32x4*)y;
    const int n4 = n >> 2;

    float acc = 0.f;

    if (n4 == NBLOCKS * NTHREADS * VPT) {
        if (threadIdx.x < NUM_LEVELS) s_wt[threadIdx.x] = wt[threadIdx.x];
        __syncthreads();

        const int i0 = blockIdx.x * (NTHREADS * VPT) + threadIdx.x;

        // preload step 0 (4 nt loads = 64 B/lane in flight)
        f32x4 yc0 = __builtin_nontemporal_load(y4 + i0);
        f32x4 yc1 = __builtin_nontemporal_load(y4 + i0 + NTHREADS);
        f32x4 xc0 = __builtin_nontemporal_load(x4 + i0);
        f32x4 xc1 = __builtin_nontemporal_load(x4 + i0 + NTHREADS);

        float a0 = 0.f, a1 = 0.f;
        #pragma unroll
        for (int k = 0; k < OUTER; ++k) {
            f32x4 yn0, yn1, xn0, xn1;
            if (k < OUTER - 1) {
                const int in = i0 + (k + 1) * (2 * NTHREADS);
                yn0 = __builtin_nontemporal_load(y4 + in);
                yn1 = __builtin_nontemporal_load(y4 + in + NTHREADS);
                xn0 = __builtin_nontemporal_load(x4 + in);
                xn1 = __builtin_nontemporal_load(x4 + in + NTHREADS);
            }
            // waits for CURRENT land here; next-step loads stay in flight
            PIN4(yc0); PIN4(yc1); PIN4(xc0); PIN4(xc1);
            GATHER_ACC(yc0, xc0);
            GATHER_ACC(yc1, xc1);
            if (k < OUTER - 1) {
                yc0 = yn0; yc1 = yn1; xc0 = xn0; xc1 = xn1;
            }
        }
        acc = a0 + a1;
    } else {
        // Generic fallback path (grid-stride, normal loads).
        for (int i = threadIdx.x; i < NUM_LEVELS; i += NTHREADS) s_wt[i] = wt[i];
        __syncthreads();
        const int stride = NBLOCKS * NTHREADS;
        float a0 = 0.f, a1 = 0.f;
        for (int i = blockIdx.x * NTHREADS + threadIdx.x; i < n4; i += stride) {
            f32x4 xv = x4[i], yv = y4[i];
            GATHER_ACC(yv, xv);
        }
        acc = a0 + a1;
    }

    // wave-64 shuffle reduction
    #pragma unroll
    for (int off = 32; off > 0; off >>= 1)
        acc += __shfl_down(acc, off, 64);

    const int lane = threadIdx.x & 63;
    const int wave = threadIdx.x >> 6;
    if (lane == 0) s_red[wave] = acc;
    __syncthreads();
    if (threadIdx.x == 0) {
        float s = 0.f;
        #pragma unroll
        for (int w = 0; w < NTHREADS / 64; ++w) s += s_red[w];
        partial[blockIdx.x] = s;   // plain store, no atomic
    }
}

// Stage 2: one block folds the partials and writes the final mean.
// Overwrites the poisoned output directly -> no memset node needed.
__global__ __launch_bounds__(NTHREADS) void wmse_reduce(
    const float* __restrict__ partial, float* __restrict__ out, float inv_n)
{
    __shared__ float s_red[NTHREADS / 64];
    float acc = 0.f;
    #pragma unroll
    for (int k = 0; k < NBLOCKS / NTHREADS; ++k)
        acc += partial[threadIdx.x + k * NTHREADS];

    #pragma unroll
    for (int off = 32; off > 0; off >>= 1)
        acc += __shfl_down(acc, off, 64);

    const int lane = threadIdx.x & 63;
    const int wave = threadIdx.x >> 6;
    if (lane == 0) s_red[wave] = acc;
    __syncthreads();
    if (threadIdx.x == 0) {
        float s = 0.f;
        #pragma unroll
        for (int w = 0; w < NTHREADS / 64; ++w) s += s_red[w];
        *out = s * inv_n;
    }
}

// Fallback (workspace too small): atomic single-kernel version.
__global__ __launch_bounds__(NTHREADS) void wmse_fused_atomic(
    const float* __restrict__ x,
    const float* __restrict__ y,
    const float* __restrict__ wt,
    float* __restrict__ out, int n, float inv_n)
{
    __shared__ float s_wt[NUM_LEVELS];
    __shared__ float s_red[NTHREADS / 64];

    for (int i = threadIdx.x; i < NUM_LEVELS; i += NTHREADS) s_wt[i] = wt[i];
    __syncthreads();

    const f32x4* __restrict__ x4 = (const f32x4*)x;
    const f32x4* __restrict__ y4 = (const f32x4*)y;
    const int n4 = n >> 2;
    const int stride = NBLOCKS * NTHREADS;
    const int base = blockIdx.x * NTHREADS + threadIdx.x;

    float a0 = 0.f, a1 = 0.f;
    for (int i = base; i < n4; i += stride) {
        f32x4 xv = x4[i], yv = y4[i];
        GATHER_ACC(yv, xv);
    }
    float acc = a0 + a1;

    #pragma unroll
    for (int off = 32; off > 0; off >>= 1)
        acc += __shfl_down(acc, off, 64);

    const int lane = threadIdx.x & 63;
    const int wave = threadIdx.x >> 6;
    if (lane == 0) s_red[wave] = acc;
    __syncthreads();
    if (threadIdx.x == 0) {
        float s = 0.f;
        #pragma unroll
        for (int w = 0; w < NTHREADS / 64; ++w) s += s_red[w];
        atomicAdd(out, s * inv_n);
    }
}

extern "C" void kernel_launch(void* const* d_in, const int* in_sizes, int n_in,
                              void* d_out, int out_size, void* d_ws, size_t ws_size,
                              hipStream_t stream) {
    const float* x  = (const float*)d_in[0];
    const float* y  = (const float*)d_in[1];
    const float* wt = (const float*)d_in[2];
    float* out = (float*)d_out;
    const int n = in_sizes[0];
    const float inv_n = 1.0f / (float)n;

    if (d_ws && ws_size >= NBLOCKS * sizeof(float)) {
        float* partial = (float*)d_ws;
        wmse_partial<<<NBLOCKS, NTHREADS, 0, stream>>>(x, y, wt, partial, n);
        wmse_reduce<<<1, NTHREADS, 0, stream>>>(partial, out, inv_n);
    } else {
        hipMemsetAsync(out, 0, sizeof(float), stream);
        wmse_fused_atomic<<<NBLOCKS, NTHREADS, 0, stream>>>(x, y, wt, out, n, inv_n);
    }
}